// Round 1
// baseline (317.943 us; speedup 1.0000x reference)
//
#include <hip/hip_runtime.h>
#include <math.h>

#define LSEQ 1024
#define NB 16
#define NC 12
#define NH 256
#define NM 32
#define NS 3
#define TWO_PI 6.283185307179586f

// ---- workspace layout (float offsets) ----
#define OFF_MEANS 0          // 192
#define OFF_STDEV 192        // 192
#define OFF_EBAR  384        // 768
#define OFF_EPART 1152       // 96*256 = 24576 partials for ebar
#define OFF_WT_RE 25728      // S*K*N = 24576
#define OFF_WT_IM 50304      // 24576
#define OFF_V     74880      // S*N*L = 786432
#define OFF_P0    861312     // S*N*N = 196608
#define OFF_P1    1057920    // 196608
#define OFF_UT_RE 1254528    // S*K*L = 98304
#define OFF_UT_IM 1352832    // 98304
#define OFF_H     1451136    // 1024
#define OFF_FEAT  1452160    // 192
// total 1452352 floats = 5.81 MB

__device__ __forceinline__ float block_reduce_sum(float v, float* sbuf) {
  int t = threadIdx.x;
  sbuf[t] = v; __syncthreads();
  for (int off = 128; off > 0; off >>= 1) {
    if (t < off) sbuf[t] += sbuf[t + off];
    __syncthreads();
  }
  float r = sbuf[0];
  __syncthreads();
  return r;
}

// per-(b,c) mean and stdev of x_enc over seq axis
__global__ __launch_bounds__(256) void k_stats(const float* __restrict__ x,
                                               float* __restrict__ means,
                                               float* __restrict__ stdev) {
  int bc = blockIdx.x; int b = bc / NC, c = bc % NC;
  __shared__ float xs[LSEQ];
  __shared__ float red[256];
  int t = threadIdx.x;
  for (int e = 0; e < 4; ++e) {
    int tau = t + 256 * e;
    xs[tau] = x[((size_t)b * LSEQ + tau) * NC + c];
  }
  __syncthreads();
  float p = 0.f;
  for (int e = 0; e < 4; ++e) p += xs[t + 256 * e];
  float sum = block_reduce_sum(p, red);
  float mean = sum * (1.0f / LSEQ);
  float q = 0.f;
  for (int e = 0; e < 4; ++e) { float d = xs[t + 256 * e] - mean; q += d * d; }
  float sq = block_reduce_sum(q, red);
  if (t == 0) {
    means[bc] = mean;
    stdev[bc] = sqrtf(sq * (1.0f / LSEQ) + 1e-5f);
  }
}

// ebar partials: grid (NS*32), each block sums 32 rows of eval_last
__global__ __launch_bounds__(256) void k_ebar_part(const float* __restrict__ ev,
                                                   float* __restrict__ epart) {
  int blk = blockIdx.x;          // s*32 + chunk
  int s = blk >> 5, ch = blk & 31;
  int o = threadIdx.x;
  float acc = 0.f;
  const float* base = ev + (size_t)s * LSEQ * NH + (size_t)ch * 32 * NH + o;
  for (int l = 0; l < 32; ++l) acc += base[(size_t)l * NH];
  epart[(size_t)blk * NH + o] = acc;
}

__global__ __launch_bounds__(256) void k_ebar_final(const float* __restrict__ epart,
                                                    float* __restrict__ ebar) {
  int s = blockIdx.x; int o = threadIdx.x;
  float acc = 0.f;
  for (int ch = 0; ch < 32; ++ch) acc += epart[((size_t)(s * 32 + ch)) * NH + o];
  ebar[s * NH + o] = acc * (1.0f / LSEQ);
}

// V[:, 0] = B
__global__ void k_initV(const float* __restrict__ Bv, float* __restrict__ V) {
  int idx = blockIdx.x * 256 + threadIdx.x; // 0..767 = s*NH+i
  V[(size_t)idx * LSEQ] = Bv[idx];
}

// wt[s,k,i] = sum_o ebar[s,o] * w_spec[s,i,o,k]   (re and im)
__global__ __launch_bounds__(256) void k_wtilde(const float* __restrict__ wre,
                                                const float* __restrict__ wim,
                                                const float* __restrict__ ebar,
                                                float* __restrict__ wt_re,
                                                float* __restrict__ wt_im) {
  int blk = blockIdx.x; int s = blk / NH, i = blk % NH;
  int t = threadIdx.x;
  __shared__ float ebs[NH];
  __shared__ float sr[256], si_[256];
  ebs[t] = ebar[s * NH + t];
  __syncthreads();
  const float* br = wre + (size_t)(s * NH + i) * NH * NM;
  const float* bi = wim + (size_t)(s * NH + i) * NH * NM;
  float accR = 0.f, accI = 0.f;
  int g = t >> 5;
  for (int it = 0; it < 32; ++it) {
    int o = g + 8 * it;
    float e = ebs[o];
    int idx = t + 256 * it;   // == o*32 + k, coalesced
    accR += e * br[idx];
    accI += e * bi[idx];
  }
  sr[t] = accR; si_[t] = accI;
  __syncthreads();
  if (t < 32) {
    float aR = 0.f, aI = 0.f;
    for (int gg = 0; gg < 8; ++gg) { aR += sr[gg * 32 + t]; aI += si_[gg * 32 + t]; }
    wt_re[(size_t)(s * NM + t) * NH + i] = aR;
    wt_im[(size_t)(s * NM + t) * NH + i] = aI;
  }
}

// one doubling step: job0: V[:, m..2m-1] = P @ V[:, 0..m-1]; job1: Pnext = P @ P
__global__ __launch_bounds__(256) void k_gemm_step(const float* __restrict__ Pcur,
                                                   float* __restrict__ Pnext,
                                                   float* __restrict__ V,
                                                   int m, int doSquare) {
  int z = blockIdx.z; int s = z >> 1, job = z & 1;
  const float *Amat, *Bmat; float* Cmat; int ncols, ldb, ldc;
  if (job == 0) {
    Amat = Pcur + (size_t)s * NH * NH;
    Bmat = V + (size_t)s * NH * LSEQ;
    Cmat = V + (size_t)s * NH * LSEQ + m;
    ncols = m; ldb = LSEQ; ldc = LSEQ;
  } else {
    if (!doSquare) return;
    Amat = Pcur + (size_t)s * NH * NH;
    Bmat = Amat;
    Cmat = Pnext + (size_t)s * NH * NH;
    ncols = NH; ldb = NH; ldc = NH;
  }
  int bx = blockIdx.x, by = blockIdx.y;
  if (bx * 64 >= ncols) return;
  __shared__ float As[16][68];
  __shared__ float Bs[16][68];
  int tid = threadIdx.x;
  int tx = tid & 15, ty = tid >> 4;
  float acc[4][4] = {{0.f}};
  int row0 = by * 64, col0 = bx * 64;
  int kkA = tid & 15, iA = tid >> 4;
  int jB = tid & 63, kkB = tid >> 6;
  for (int k0 = 0; k0 < NH; k0 += 16) {
    for (int p = 0; p < 4; ++p)
      As[kkA][iA + 16 * p] = Amat[(size_t)(row0 + iA + 16 * p) * NH + k0 + kkA];
    for (int p = 0; p < 4; ++p) {
      int col = col0 + jB;
      Bs[kkB + 4 * p][jB] = (col < ncols) ? Bmat[(size_t)(k0 + kkB + 4 * p) * ldb + col] : 0.0f;
    }
    __syncthreads();
    #pragma unroll
    for (int kk = 0; kk < 16; ++kk) {
      float4 av = *(const float4*)&As[kk][ty * 4];
      float4 bv = *(const float4*)&Bs[kk][tx * 4];
      acc[0][0] += av.x * bv.x; acc[0][1] += av.x * bv.y; acc[0][2] += av.x * bv.z; acc[0][3] += av.x * bv.w;
      acc[1][0] += av.y * bv.x; acc[1][1] += av.y * bv.y; acc[1][2] += av.y * bv.z; acc[1][3] += av.y * bv.w;
      acc[2][0] += av.z * bv.x; acc[2][1] += av.z * bv.y; acc[2][2] += av.z * bv.z; acc[2][3] += av.z * bv.w;
      acc[3][0] += av.w * bv.x; acc[3][1] += av.w * bv.y; acc[3][2] += av.w * bv.z; acc[3][3] += av.w * bv.w;
    }
    __syncthreads();
  }
  for (int ii = 0; ii < 4; ++ii) {
    int r = row0 + ty * 4 + ii;
    for (int jj = 0; jj < 4; ++jj) {
      int c2 = col0 + tx * 4 + jj;
      if (c2 < ncols) Cmat[(size_t)r * ldc + c2] = acc[ii][jj];
    }
  }
}

// ut[s,k,d] = sum_i wt[s,k,i] * V[s,i,d]  (complex via re/im weights)
__global__ __launch_bounds__(256) void k_ut(const float* __restrict__ wt_re,
                                            const float* __restrict__ wt_im,
                                            const float* __restrict__ V,
                                            float* __restrict__ ut_re,
                                            float* __restrict__ ut_im) {
  int blk = blockIdx.x;   // s*NM + k
  int t = threadIdx.x;
  const float* wr = wt_re + (size_t)blk * NH;
  const float* wi_ = wt_im + (size_t)blk * NH;
  int s = blk / NM;
  const float* Vs = V + (size_t)s * NH * LSEQ;
  float ar[4] = {0.f, 0.f, 0.f, 0.f}, ai[4] = {0.f, 0.f, 0.f, 0.f};
  for (int i = 0; i < NH; ++i) {
    float a = wr[i], b = wi_[i];
    const float* vrow = Vs + (size_t)i * LSEQ + t;
    #pragma unroll
    for (int e = 0; e < 4; ++e) {
      float v = vrow[256 * e];
      ar[e] += a * v; ai[e] += b * v;
    }
  }
  for (int e = 0; e < 4; ++e) {
    ut_re[(size_t)blk * LSEQ + t + 256 * e] = ar[e];
    ut_im[(size_t)blk * LSEQ + t + 256 * e] = ai[e];
  }
}

// in-place: ut[k,d] -> prefix_{d' <= d} e^{-i w_k d'} ut[k,d']
__global__ __launch_bounds__(256) void k_scan(float* __restrict__ ut_re,
                                              float* __restrict__ ut_im) {
  int blk = blockIdx.x; int k = blk & 31;
  int t = threadIdx.x;
  float* ur = ut_re + (size_t)blk * LSEQ;
  float* ui = ut_im + (size_t)blk * LSEQ;
  __shared__ float sr[LSEQ], si_[LSEQ];
  __shared__ float cr[256], ci[256];
  for (int e = 0; e < 4; ++e) {
    int d = t + 256 * e;
    int frac = (k * d) & 1023;
    float ang = -(TWO_PI / 1024.0f) * (float)frac;
    float sn, csn; sincosf(ang, &sn, &csn);
    float re = ur[d], im = ui[d];
    sr[d] = re * csn - im * sn;
    si_[d] = re * sn + im * csn;
  }
  __syncthreads();
  float lr[4], li[4], rr = 0.f, ii = 0.f;
  for (int e = 0; e < 4; ++e) {
    rr += sr[4 * t + e]; ii += si_[4 * t + e];
    lr[e] = rr; li[e] = ii;
  }
  cr[t] = rr; ci[t] = ii;
  __syncthreads();
  for (int off = 1; off < 256; off <<= 1) {
    float pr = 0.f, pi = 0.f;
    if (t >= off) { pr = cr[t - off]; pi = ci[t - off]; }
    __syncthreads();
    cr[t] += pr; ci[t] += pi;
    __syncthreads();
  }
  float offr = (t > 0) ? cr[t - 1] : 0.0f;
  float offi = (t > 0) ? ci[t - 1] : 0.0f;
  for (int e = 0; e < 4; ++e) {
    ur[4 * t + e] = lr[e] + offr;
    ui[4 * t + e] = li[e] + offi;
  }
}

// H[tau] = sum_s w_mlp[s] * Re sum_k alpha_k e^{-i w_k tau} S_s[k, L-1-tau]
__global__ __launch_bounds__(256) void k_H(const float* __restrict__ ut_re,
                                           const float* __restrict__ ut_im,
                                           const float* __restrict__ w_mlp,
                                           float* __restrict__ H) {
  int tau = blockIdx.x * 256 + threadIdx.x;
  int mIdx = 1023 - tau;
  float acc = 0.0f;
  for (int s = 0; s < NS; ++s) {
    float wm = w_mlp[s];
    const float* Sr = ut_re + (size_t)s * NM * LSEQ;
    const float* Si = ut_im + (size_t)s * NM * LSEQ;
    float partial = Sr[mIdx] * (1.0f / LSEQ);  // k = 0
    for (int k = 1; k < NM; ++k) {
      int frac = (k * (tau + 1)) & 1023;
      float ang = -(TWO_PI / 1024.0f) * (float)frac;
      float sn, csn; sincosf(ang, &sn, &csn);
      float r = Sr[(size_t)k * LSEQ + mIdx];
      float im = Si[(size_t)k * LSEQ + mIdx];
      partial += (2.0f / LSEQ) * (r * csn - im * sn);
    }
    acc += wm * partial;
  }
  H[tau] = acc;
}

// feat[b,c] = (dot(f, H) + b_mlp - ab)/(aw+1e-10)*stdev + mean
__global__ __launch_bounds__(256) void k_feat(const float* __restrict__ x,
                                              const float* __restrict__ means,
                                              const float* __restrict__ stdev,
                                              const float* __restrict__ aw,
                                              const float* __restrict__ ab,
                                              const float* __restrict__ b_mlp,
                                              const float* __restrict__ H,
                                              float* __restrict__ feat) {
  int bc = blockIdx.x; int b = bc / NC, c = bc % NC;
  __shared__ float red[256];
  int t = threadIdx.x;
  float mn = means[bc], sd = stdev[bc];
  float w = aw[c], bb = ab[c];
  float acc = 0.f;
  for (int e = 0; e < 4; ++e) {
    int tau = t + 256 * e;
    float xv = x[((size_t)b * LSEQ + tau) * NC + c];
    float f = (xv - mn) / sd * w + bb;
    acc += f * H[tau];
  }
  float sum = block_reduce_sum(acc, red);
  if (t == 0) {
    float mr = sum + b_mlp[0];
    feat[bc] = (mr - bb) / (w + 1e-10f) * sd + mn;
  }
}

__global__ void k_out(const float* __restrict__ feat, const float* __restrict__ w_fc,
                      const float* __restrict__ b_fc, float* __restrict__ out) {
  int t = threadIdx.x;
  if (t < NB * 5) {
    int b = t / 5, d = t % 5;
    float acc = b_fc[d];
    for (int c = 0; c < NC; ++c) acc += feat[b * NC + c] * w_fc[d * NC + c];
    out[t] = acc;
  }
}

extern "C" void kernel_launch(void* const* d_in, const int* in_sizes, int n_in,
                              void* d_out, int out_size, void* d_ws, size_t ws_size,
                              hipStream_t stream) {
  const float* x_enc   = (const float*)d_in[0];
  const float* aw      = (const float*)d_in[1];
  const float* ab      = (const float*)d_in[2];
  const float* wre     = (const float*)d_in[3];
  const float* wim     = (const float*)d_in[4];
  const float* w_mlp   = (const float*)d_in[5];
  const float* b_mlp   = (const float*)d_in[6];
  const float* w_fc    = (const float*)d_in[7];
  const float* b_fc    = (const float*)d_in[8];
  const float* A_mats  = (const float*)d_in[9];
  const float* B_vecs  = (const float*)d_in[10];
  const float* ev      = (const float*)d_in[11];

  float* ws    = (float*)d_ws;
  float* means = ws + OFF_MEANS;
  float* stdev = ws + OFF_STDEV;
  float* ebar  = ws + OFF_EBAR;
  float* epart = ws + OFF_EPART;
  float* wt_re = ws + OFF_WT_RE;
  float* wt_im = ws + OFF_WT_IM;
  float* V     = ws + OFF_V;
  float* P0    = ws + OFF_P0;
  float* P1    = ws + OFF_P1;
  float* ut_re = ws + OFF_UT_RE;
  float* ut_im = ws + OFF_UT_IM;
  float* H     = ws + OFF_H;
  float* feat  = ws + OFF_FEAT;
  float* out   = (float*)d_out;

  k_initV<<<3, 256, 0, stream>>>(B_vecs, V);
  k_stats<<<192, 256, 0, stream>>>(x_enc, means, stdev);
  k_ebar_part<<<NS * 32, 256, 0, stream>>>(ev, epart);
  k_ebar_final<<<NS, 256, 0, stream>>>(epart, ebar);
  k_wtilde<<<NS * NH, 256, 0, stream>>>(wre, wim, ebar, wt_re, wt_im);

  // Krylov doubling: V_{2m} = [V_m | P_m V_m], P_{2m} = P_m^2
  const float* Pc = A_mats;  // P_1 = A
  float* Pn = P0;
  for (int m = 1; m <= 512; m <<= 1) {
    int doSq = (m < 512);
    k_gemm_step<<<dim3(8, 4, 6), 256, 0, stream>>>(Pc, Pn, V, m, doSq);
    Pc = Pn;
    Pn = (Pn == P0) ? P1 : P0;
  }

  k_ut<<<NS * NM, 256, 0, stream>>>(wt_re, wt_im, V, ut_re, ut_im);
  k_scan<<<NS * NM, 256, 0, stream>>>(ut_re, ut_im);
  k_H<<<4, 256, 0, stream>>>(ut_re, ut_im, w_mlp, H);
  k_feat<<<192, 256, 0, stream>>>(x_enc, means, stdev, aw, ab, b_mlp, H, feat);
  k_out<<<1, 128, 0, stream>>>(feat, w_fc, b_fc, out);
}